// Round 1
// 363.387 us; speedup vs baseline: 1.2236x; 1.2236x over previous
//
#include <hip/hip_runtime.h>

typedef __bf16 bf16x8 __attribute__((ext_vector_type(8)));
typedef float  f32x4  __attribute__((ext_vector_type(4)));
typedef float  f32x16 __attribute__((ext_vector_type(16)));

__device__ __forceinline__ unsigned short f2b(float f) {
    union { float f; unsigned int v; } c; c.f = f;
    unsigned int u = c.v;
    unsigned int r = u + 0x7FFFu + ((u >> 16) & 1u);   // RNE
    return (unsigned short)(r >> 16);
}
__device__ __forceinline__ f32x4 mfma16(bf16x8 a, bf16x8 b, f32x4 c) {
    return __builtin_amdgcn_mfma_f32_16x16x32_bf16(a, b, c, 0, 0, 0);
}
__device__ __forceinline__ f32x16 mfma32(bf16x8 a, bf16x8 b, f32x16 c) {
    return __builtin_amdgcn_mfma_f32_32x32x16_bf16(a, b, c, 0, 0, 0);
}
// pack two f32 -> 2xbf16 in one u32 (lo = a, hi = b), RNE
__device__ __forceinline__ unsigned cvtpk(float a, float b) {
    unsigned r;
    asm("v_cvt_pk_bf16_f32 %0, %1, %2" : "=v"(r) : "v"(a), "v"(b));
    return r;
}

// ---------------- constants ----------------
#define BB 8
#define SS 2048
#define DD 256
#define HH 4
#define FF 512
#define MM (BB * SS)   // 16384

// ---------------- transpose f32 -> bf16 with scale ----------------
__global__ __launch_bounds__(256) void transpose_f32_kernel(
    const float* __restrict__ in, unsigned short* __restrict__ out,
    int inS, int outS, long long inZa, long long inZb, int zmod, long long outZ,
    float scale)
{
    __shared__ unsigned short T[64][72];
    const int z = blockIdx.z;
    in  += (long long)(z / zmod) * inZa + (long long)(z % zmod) * inZb;
    out += (long long)z * outZ;
    const int r0 = blockIdx.x * 64, c0 = blockIdx.y * 64;
    const int tid = threadIdx.x;
    const int row = tid >> 3;           // 0..31
    const int col = (tid & 7) * 8;      // 0..56
#pragma unroll
    for (int c = 0; c < 2; ++c) {
        int rr = c * 32 + row;
        const float4 a = *reinterpret_cast<const float4*>(&in[(long long)(r0 + rr) * inS + c0 + col]);
        const float4 b = *reinterpret_cast<const float4*>(&in[(long long)(r0 + rr) * inS + c0 + col + 4]);
        alignas(16) unsigned short t[8] = {
            f2b(a.x * scale), f2b(a.y * scale), f2b(a.z * scale), f2b(a.w * scale),
            f2b(b.x * scale), f2b(b.y * scale), f2b(b.z * scale), f2b(b.w * scale) };
        *reinterpret_cast<uint4*>(&T[rr][col]) = *reinterpret_cast<const uint4*>(t);
    }
    __syncthreads();
#pragma unroll
    for (int c = 0; c < 2; ++c) {
        int orow = c * 32 + row;
        alignas(16) unsigned short tmp[8];
#pragma unroll
        for (int j = 0; j < 8; ++j) tmp[j] = T[col + j][orow];
        *reinterpret_cast<uint4*>(&out[(long long)(c0 + orow) * outS + r0 + col]) =
            *reinterpret_cast<const uint4*>(tmp);
    }
}

// ---------------- bias concat: qkb[2048] = {bq*1/16, bk}, vb[1024] = bv ----------------
__global__ __launch_bounds__(256) void bias_concat_kernel(
    const float* __restrict__ bq, const float* __restrict__ bk,
    const float* __restrict__ bv, float* __restrict__ qkb, float* __restrict__ vb)
{
    const int i = blockIdx.x * 256 + threadIdx.x;
    if (i < 1024)       qkb[i] = bq[i] * 0.0625f;
    else if (i < 2048)  qkb[i] = bk[i - 1024];
    else                vb[i - 2048] = bv[i - 2048];
}

// ---------------- LayerNorm: one wave per 256-elem row, f32 in -> bf16 out ----------------
__global__ __launch_bounds__(256) void ln_kernel(
    const float* __restrict__ in, const float* __restrict__ g,
    const float* __restrict__ bta, unsigned short* __restrict__ out)
{
    const int tid  = threadIdx.x;
    const int wave = tid >> 6, lane = tid & 63;
    const int row  = blockIdx.x * 4 + wave;
    const float4 v = reinterpret_cast<const float4*>(in)[(long long)row * 64 + lane];
    float x[4] = { v.x, v.y, v.z, v.w };
    float s = x[0] + x[1] + x[2] + x[3];
    float q = x[0]*x[0] + x[1]*x[1] + x[2]*x[2] + x[3]*x[3];
#pragma unroll
    for (int off = 1; off < 64; off <<= 1) {
        s += __shfl_xor(s, off);
        q += __shfl_xor(q, off);
    }
    const float mean = s * (1.0f / 256.0f);
    const float var  = q * (1.0f / 256.0f) - mean * mean;
    const float rs   = rsqrtf(var + 1e-5f);
    const float4 gv = reinterpret_cast<const float4*>(g)[lane];
    const float4 bv = reinterpret_cast<const float4*>(bta)[lane];
    unsigned short y[4];
    y[0] = f2b((x[0] - mean) * rs * gv.x + bv.x);
    y[1] = f2b((x[1] - mean) * rs * gv.y + bv.y);
    y[2] = f2b((x[2] - mean) * rs * gv.z + bv.z);
    y[3] = f2b((x[3] - mean) * rs * gv.w + bv.w);
    uint2 o;
    o.x = (unsigned int)y[0] | ((unsigned int)y[1] << 16);
    o.y = (unsigned int)y[2] | ((unsigned int)y[3] << 16);
    reinterpret_cast<uint2*>(out)[(long long)row * 64 + lane] = o;
}

// ---------------- GEMM: C[MxN] = A[MxK] @ B  (B given as BT[N x K], bf16) ----------------
template <bool RELU, int RES, bool OUTBF, int NS, bool VT>
__global__ __launch_bounds__(256) void gemm_kernel(
    const unsigned short* __restrict__ A, const unsigned short* __restrict__ BT,
    const float* __restrict__ bias, const float* __restrict__ res,
    void* __restrict__ out, int M, int N, int K)
{
    __shared__ unsigned short As[128 * 40];
    __shared__ unsigned short Bs[(NS == 4 ? 128 : 64) * 40];
    const int tid  = threadIdx.x;
    const int wave = tid >> 6, lane = tid & 63;
    const int quad = lane >> 4, l16 = lane & 15;
    const int wm = wave >> 1, wn = wave & 1;
    const int WN = NS * 16;                        // wave n-width
    const int m0 = blockIdx.x * 128, n0 = blockIdx.y * (2 * WN);

    f32x4 acc[4][NS];
#pragma unroll
    for (int i = 0; i < 4; ++i)
#pragma unroll
        for (int j = 0; j < NS; ++j) acc[i][j] = (f32x4){0.f, 0.f, 0.f, 0.f};

    const int srow = tid >> 2;          // 0..63
    const int scol = (tid & 3) * 8;     // 0,8,16,24

    for (int k0 = 0; k0 < K; k0 += 32) {
        __syncthreads();
#pragma unroll
        for (int c = 0; c < 2; ++c) {
            const int r = c * 64 + srow;
            *reinterpret_cast<uint4*>(&As[r * 40 + scol]) =
                *reinterpret_cast<const uint4*>(&A[(long long)(m0 + r) * K + k0 + scol]);
        }
        {
            *reinterpret_cast<uint4*>(&Bs[srow * 40 + scol]) =
                *reinterpret_cast<const uint4*>(&BT[(long long)(n0 + srow) * K + k0 + scol]);
            if (NS == 4) {
                const int r = 64 + srow;
                *reinterpret_cast<uint4*>(&Bs[r * 40 + scol]) =
                    *reinterpret_cast<const uint4*>(&BT[(long long)(n0 + r) * K + k0 + scol]);
            }
        }
        __syncthreads();
        bf16x8 af[4], bf[NS];
#pragma unroll
        for (int ms = 0; ms < 4; ++ms)
            af[ms] = *reinterpret_cast<const bf16x8*>(&As[(wm * 64 + ms * 16 + l16) * 40 + quad * 8]);
#pragma unroll
        for (int ns = 0; ns < NS; ++ns)
            bf[ns] = *reinterpret_cast<const bf16x8*>(&Bs[(wn * WN + ns * 16 + l16) * 40 + quad * 8]);
#pragma unroll
        for (int ms = 0; ms < 4; ++ms)
#pragma unroll
            for (int ns = 0; ns < NS; ++ns)
                acc[ms][ns] = mfma16(af[ms], bf[ns], acc[ms][ns]);
    }

    // epilogue
#pragma unroll
    for (int ms = 0; ms < 4; ++ms) {
#pragma unroll
        for (int ns = 0; ns < NS; ++ns) {
            const int cg = n0 + wn * WN + ns * 16 + l16;
            const float bvc = VT ? 0.f : bias[cg];
#pragma unroll
            for (int r = 0; r < 4; ++r) {
                const int rg = m0 + wm * 64 + ms * 16 + quad * 4 + r;
                float v = acc[ms][ns][r] + (VT ? bias[rg] : bvc);
                if (RELU)   v = fmaxf(v, 0.0f);
                if (RES == 1)
                    v += res[(long long)rg * N + cg];
                if (VT) {
                    const long long oaddr =
                        (long long)((cg >> 11) * 4 + (rg >> 8)) * 524288 +
                        (long long)(rg & 255) * 2048 + (cg & 2047);
                    reinterpret_cast<unsigned short*>(out)[oaddr] = f2b(v);
                } else if (OUTBF) {
                    reinterpret_cast<unsigned short*>(out)[(long long)rg * N + cg] = f2b(v);
                } else {
                    reinterpret_cast<float*>(out)[(long long)rg * N + cg] = v;
                }
            }
        }
    }
}

// ---------------- Flash attention, swapped-QK^T + in-register P (T12),
// double-buffered K/V with async reg staging (T14), 1 barrier/iter.
// grid (B*H, S/128): 4 waves x 32 q-rows. LDS: 2*(32*264 + 256*40)*2B = 74752 B -> 2 blocks/CU.
__global__ __launch_bounds__(256, 2) void attn_kernel(
    const unsigned short* __restrict__ QK, const unsigned short* __restrict__ Vt,
    unsigned short* __restrict__ Cat)
{
    __shared__ __align__(16) unsigned short Ks[2][32 * 264];   // [t][d], stride 264 (132 dw == 4 mod 32: conflict-free)
    __shared__ __align__(16) unsigned short Vs[2][256 * 40];   // [e][t], stride 40  (20 dw: conflict-free)
    const int tid  = threadIdx.x;
    const int wave = tid >> 6, lane = tid & 63;
    const int l32 = lane & 31, half = lane >> 5;
    const int by = blockIdx.x;              // b*4 + h
    const int h = by & 3, b = by >> 2;
    const int q0 = blockIdx.y * 128;
    const unsigned short* Qb = QK + (long long)b * SS * 2048 + h * 256;
    const unsigned short* Kb = Qb + 1024;
    const unsigned short* vbase = Vt + (long long)by * DD * SS;

    // Q fragments, 32 rows/wave: lane holds Q[q0+w*32+l32][kb*16 + half*8 + j]
    bf16x8 qf[16];
    {
        const unsigned short* qrow = Qb + (long long)(q0 + wave * 32 + l32) * 2048 + half * 8;
#pragma unroll
        for (int kb = 0; kb < 16; ++kb)
            qf[kb] = *reinterpret_cast<const bf16x8*>(qrow + kb * 16);
    }

    f32x16 o[8];
#pragma unroll
    for (int i = 0; i < 8; ++i)
#pragma unroll
        for (int r = 0; r < 16; ++r) o[i][r] = 0.f;
    float lsum = 0.f;   // per-lane partial row-sum for q = l32 (this half's t-subset)

    const int krow = tid >> 3;          // 0..31
    const int kcol = (tid & 7) * 8;     // 0..56 (shorts)
    const int ve   = tid >> 2;          // 0..63 (base V row)
    const int vtf  = (tid & 3) * 8;     // 0..24 (t offset, shorts)

    uint4 kreg[4], vreg[4];
    // prologue: stage tile 0 into buffer 0
#pragma unroll
    for (int c = 0; c < 4; ++c)
        kreg[c] = *reinterpret_cast<const uint4*>(&Kb[(long long)krow * 2048 + kcol + c * 64]);
#pragma unroll
    for (int c = 0; c < 4; ++c)
        vreg[c] = *reinterpret_cast<const uint4*>(&vbase[(long long)(ve + c * 64) * SS + vtf]);
#pragma unroll
    for (int c = 0; c < 4; ++c)
        *reinterpret_cast<uint4*>(&Ks[0][krow * 264 + kcol + c * 64]) = kreg[c];
#pragma unroll
    for (int c = 0; c < 4; ++c)
        *reinterpret_cast<uint4*>(&Vs[0][(ve + c * 64) * 40 + vtf]) = vreg[c];
    __syncthreads();

    for (int t = 0; t < 64; ++t) {
        const int cur = t & 1;
        // issue next-tile global loads early (latency hides under compute)
        if (t < 63) {
            const int t1 = (t + 1) * 32;
#pragma unroll
            for (int c = 0; c < 4; ++c)
                kreg[c] = *reinterpret_cast<const uint4*>(&Kb[(long long)(t1 + krow) * 2048 + kcol + c * 64]);
#pragma unroll
            for (int c = 0; c < 4; ++c)
                vreg[c] = *reinterpret_cast<const uint4*>(&vbase[(long long)(ve + c * 64) * SS + t1 + vtf]);
        }

        // swapped QK^T: sc = K_tile . Q^T -> lane holds S[q=l32][t-subset], split acc chain
        f32x16 sc0, sc1;
#pragma unroll
        for (int r = 0; r < 16; ++r) { sc0[r] = 0.f; sc1[r] = 0.f; }
        __builtin_amdgcn_s_setprio(1);
#pragma unroll
        for (int kb = 0; kb < 8; ++kb) {
            bf16x8 kf0 = *reinterpret_cast<const bf16x8*>(&Ks[cur][l32 * 264 + (2 * kb) * 16 + half * 8]);
            bf16x8 kf1 = *reinterpret_cast<const bf16x8*>(&Ks[cur][l32 * 264 + (2 * kb + 1) * 16 + half * 8]);
            sc0 = mfma32(kf0, qf[2 * kb], sc0);
            sc1 = mfma32(kf1, qf[2 * kb + 1], sc1);
        }
        __builtin_amdgcn_s_setprio(0);

        // softmax numerator: p[r] = exp(s); t(r) = (r&3) + 8*(r>>2) + 4*half
        float p[16];
#pragma unroll
        for (int r = 0; r < 16; ++r) {
            p[r] = __expf(sc0[r] + sc1[r]);
            lsum += p[r];
        }

        // pack P -> PV A-fragments fully in-register (cvt_pk + permlane32_swap)
        unsigned pk[8];
#pragma unroll
        for (int i = 0; i < 8; ++i) pk[i] = cvtpk(p[2 * i], p[2 * i + 1]);
        union { bf16x8 v; unsigned u[4]; } A0, A1;   // A0: t=0..15, A1: t=16..31
        {
            auto r = __builtin_amdgcn_permlane32_swap(pk[0], pk[2], false, false);
            A0.u[0] = r[0]; A0.u[2] = r[1];
        }
        {
            auto r = __builtin_amdgcn_permlane32_swap(pk[1], pk[3], false, false);
            A0.u[1] = r[0]; A0.u[3] = r[1];
        }
        {
            auto r = __builtin_amdgcn_permlane32_swap(pk[4], pk[6], false, false);
            A1.u[0] = r[0]; A1.u[2] = r[1];
        }
        {
            auto r = __builtin_amdgcn_permlane32_swap(pk[5], pk[7], false, false);
            A1.u[1] = r[0]; A1.u[3] = r[1];
        }

        // PV: B = V^T tile from Vs; 8 e-tiles x 2 k-steps
        __builtin_amdgcn_s_setprio(1);
#pragma unroll
        for (int et = 0; et < 8; ++et) {
            bf16x8 vf0 = *reinterpret_cast<const bf16x8*>(&Vs[cur][(et * 32 + l32) * 40 + half * 8]);
            bf16x8 vf1 = *reinterpret_cast<const bf16x8*>(&Vs[cur][(et * 32 + l32) * 40 + 16 + half * 8]);
            o[et] = mfma32(A0.v, vf0, o[et]);
            o[et] = mfma32(A1.v, vf1, o[et]);
        }
        __builtin_amdgcn_s_setprio(0);

        // write next tile into the other buffer, then single barrier
        if (t < 63) {
            const int nxt = cur ^ 1;
#pragma unroll
            for (int c = 0; c < 4; ++c)
                *reinterpret_cast<uint4*>(&Ks[nxt][krow * 264 + kcol + c * 64]) = kreg[c];
#pragma unroll
            for (int c = 0; c < 4; ++c)
                *reinterpret_cast<uint4*>(&Vs[nxt][(ve + c * 64) * 40 + vtf]) = vreg[c];
            __syncthreads();
        }
    }

    // epilogue: full row-sum for q=l32 lives split across the two halves
    lsum += __shfl_xor(lsum, 32);
    const float inv = 1.0f / lsum;
    float invr[16];
#pragma unroll
    for (int r = 0; r < 16; ++r)
        invr[r] = __shfl(inv, (r & 3) + 8 * (r >> 2) + 4 * half);

    const int rowb = b * SS + q0 + wave * 32;
#pragma unroll
    for (int et = 0; et < 8; ++et) {
        const int cg = h * 256 + et * 32 + l32;
#pragma unroll
        for (int r = 0; r < 16; ++r) {
            const int row = (r & 3) + 8 * (r >> 2) + 4 * half;
            Cat[(long long)(rowb + row) * (HH * DD) + cg] = f2b(o[et][r] * invr[r]);
        }
    }
}

// ---------------- launch ----------------
extern "C" void kernel_launch(void* const* d_in, const int* in_sizes, int n_in,
                              void* d_out, int out_size, void* d_ws, size_t ws_size,
                              hipStream_t stream)
{
    const float* x   = (const float*)d_in[0];
    const float* Wq  = (const float*)d_in[1];
    const float* bq  = (const float*)d_in[2];
    const float* Wk  = (const float*)d_in[3];
    const float* bk  = (const float*)d_in[4];
    const float* Wv  = (const float*)d_in[5];
    const float* bv  = (const float*)d_in[6];
    const float* Wo  = (const float*)d_in[7];
    const float* bo  = (const float*)d_in[8];
    const float* g1  = (const float*)d_in[9];
    const float* be1 = (const float*)d_in[10];
    const float* g2  = (const float*)d_in[11];
    const float* be2 = (const float*)d_in[12];
    const float* W1  = (const float*)d_in[13];
    const float* bf1 = (const float*)d_in[14];
    const float* W2  = (const float*)d_in[15];
    const float* bf2 = (const float*)d_in[16];
    float* out = (float*)d_out;

    // ---- workspace layout ----
    char* ws = (char*)d_ws;
    unsigned short* xn1  = (unsigned short*)(ws + 0);           // [16384][256] bf16
    unsigned short* qk   = (unsigned short*)(ws + 8388608);     // [16384][2048] bf16 (Q|K by head)
    unsigned short* cat  = (unsigned short*)(ws + 75497472);    // [16384][1024] bf16
    unsigned short* vt   = (unsigned short*)(ws + 109051904);   // [32][256][2048] bf16
    unsigned short* wqkT = (unsigned short*)(ws + 142606336);   // [2048][256] bf16
    unsigned short* wvT  = (unsigned short*)(ws + 143654912);   // [1024][256] bf16
    unsigned short* woT  = (unsigned short*)(ws + 144179200);   // [256][1024] bf16
    unsigned short* w1T  = (unsigned short*)(ws + 144703488);   // [512][256] bf16
    unsigned short* w2T  = (unsigned short*)(ws + 144965632);   // [256][512] bf16
    float*          qkb  = (float*)(ws + 145227776);            // [2048] f32
    float*          vb   = (float*)(ws + 145235968);            // [1024] f32
    // aliases over dead regions:
    float*          xmid = (float*)(ws + 8388608);              // (qk dead after attn)
    unsigned short* xn2  = (unsigned short*)(ws + 25165824);
    unsigned short* mid  = (unsigned short*)(ws + 33554432);

    // weight transposes (scale 1/16 folded into Wq — exact, power of 2)
    transpose_f32_kernel<<<dim3(4, 4, 4),  256, 0, stream>>>(Wq, wqkT,          256,  256, 0, 65536, 4, 65536, 0.0625f);
    transpose_f32_kernel<<<dim3(4, 4, 4),  256, 0, stream>>>(Wk, wqkT + 262144, 256,  256, 0, 65536, 4, 65536, 1.0f);
    transpose_f32_kernel<<<dim3(4, 4, 4),  256, 0, stream>>>(Wv, wvT,           256,  256, 0, 65536, 4, 65536, 1.0f);
    transpose_f32_kernel<<<dim3(16, 4, 1), 256, 0, stream>>>(Wo, woT,           256, 1024, 0, 0, 4, 0, 1.0f);
    transpose_f32_kernel<<<dim3(4, 8, 1),  256, 0, stream>>>(W1, w1T,           512,  256, 0, 0, 4, 0, 1.0f);
    transpose_f32_kernel<<<dim3(8, 4, 1),  256, 0, stream>>>(W2, w2T,           256,  512, 0, 0, 4, 0, 1.0f);
    bias_concat_kernel<<<dim3(12), 256, 0, stream>>>(bq, bk, bv, qkb, vb);

    // LN1
    ln_kernel<<<dim3(4096), 256, 0, stream>>>(x, g1, be1, xn1);

    // fused Q|K projection (2048 blocks)
    gemm_kernel<false, 0, true, 4, false><<<dim3(128, 16), 256, 0, stream>>>(
        xn1, wqkT, qkb, nullptr, qk, MM, 2048, 256);
    // V^T projection straight into vt layout (1024 blocks)
    gemm_kernel<false, 0, true, 4, true><<<dim3(8, 128), 256, 0, stream>>>(
        wvT, xn1, vb, nullptr, vt, 1024, MM, 256);

    // flash attention (32x32 MFMA, 128 q-rows/block, 512 blocks = 2/CU)
    attn_kernel<<<dim3(32, 16), 256, 0, stream>>>(qk, vt, cat);

    // Wo projection + residual(x) -> xmid (f32); 128x64 tiles -> 512 blocks
    gemm_kernel<false, 1, false, 2, false><<<dim3(128, 4), 256, 0, stream>>>(
        cat, woT, bo, x, xmid, MM, 256, 1024);

    // LN2
    ln_kernel<<<dim3(4096), 256, 0, stream>>>(xmid, g2, be2, xn2);

    // FFN1 + ReLU; 128x64 tiles -> 1024 blocks
    gemm_kernel<true, 0, true, 2, false><<<dim3(128, 8), 256, 0, stream>>>(
        xn2, w1T, bf1, nullptr, mid, MM, 512, 256);

    // FFN2 + residual(xmid) -> d_out (f32); 128x64 tiles -> 512 blocks
    gemm_kernel<false, 1, false, 2, false><<<dim3(128, 4), 256, 0, stream>>>(
        mid, w2T, bf2, xmid, out, MM, 256, 512);

    (void)in_sizes; (void)n_in; (void)out_size; (void)ws_size;
}